// Round 12
// baseline (564.669 us; speedup 1.0000x reference)
//
#include <hip/hip_runtime.h>
#include <hip/hip_bf16.h>

#define NN 300000
#define EE 299999
#define AA 150000
#define DD 64
#define HH 128
#define TT 512
#define SCAN_NB2 ((2 * NN + 1023) / 1024)

typedef unsigned short u16;
typedef unsigned int u32;
typedef __attribute__((ext_vector_type(8))) short short8;
typedef __attribute__((ext_vector_type(4))) float f32x4;

// ---------- helpers ----------
__device__ __forceinline__ float bfb(u16 u) { return __uint_as_float(((u32)u) << 16); }
__device__ __forceinline__ u16 f2b(float f) {
    u32 u = __float_as_uint(f);
    u32 r = (u + 0x7FFFu + ((u >> 16) & 1u)) >> 16;
    return (u16)r;
}
__device__ __forceinline__ uint4 load8(const u16* p) { return *(const uint4*)p; }
__device__ __forceinline__ uint4 load8(const float* p) {
    float4 f1 = *(const float4*)p;
    float4 f2 = *(const float4*)(p + 4);
    union { ushort s[8]; uint4 v; } u;
    u.s[0] = f2b(f1.x); u.s[1] = f2b(f1.y); u.s[2] = f2b(f1.z); u.s[3] = f2b(f1.w);
    u.s[4] = f2b(f2.x); u.s[5] = f2b(f2.y); u.s[6] = f2b(f2.z); u.s[7] = f2b(f2.w);
    return u.v;
}
__device__ __forceinline__ void unpack8(uint4 v, float* f) {
    u32 w0 = v.x, w1 = v.y, w2 = v.z, w3 = v.w;
    f[0] = bfb((u16)w0); f[1] = bfb((u16)(w0 >> 16));
    f[2] = bfb((u16)w1); f[3] = bfb((u16)(w1 >> 16));
    f[4] = bfb((u16)w2); f[5] = bfb((u16)(w2 >> 16));
    f[6] = bfb((u16)w3); f[7] = bfb((u16)(w3 >> 16));
}
// XOR-swizzled LDS offset (u16 units): 64-k tiles, stride 64
__device__ __forceinline__ int swo(int row, int kblock) {
    return row * 64 + ((kblock ^ (row & 7)) * 8);
}
// 128-k tiles, stride 128 (kblock 0..15; xor only low 3 bits)
__device__ __forceinline__ int swo2(int row, int kblock) {
    return row * 128 + (((kblock & 8) | ((kblock & 7) ^ (row & 7))) * 8);
}
// async global->LDS, 16B per lane; dest = wave-uniform base + lane*16
__device__ __forceinline__ void gl_lds16(const u16* src, u16* ldsbase) {
    __builtin_amdgcn_global_load_lds((const __attribute__((address_space(1))) u32*)src,
                                     (__attribute__((address_space(3))) u32*)ldsbase, 16, 0, 0);
}

// ---------- weight pre-transpose ----------
__global__ __launch_bounds__(256) void k_wtrans(const float* w0, const float* w1,
                                                const float* w2, const float* w3,
                                                const float* w4, const float* w5,
                                                const float* w6, const float* w7,
                                                u16* __restrict__ wt) {
    int widx = blockIdx.x >> 3, part = blockIdx.x & 7;
    const float* W; int K = 128;
    switch (widx) {
        case 0: W = w0; break; case 1: W = w1; break;
        case 2: W = w2; break; case 3: W = w3; break;
        case 4: W = w4; break; case 5: W = w5; break;
        case 6: W = w6; break; default: W = w7; K = 64; break;
    }
    u16* dst = wt + widx * 16384;
    int total = K * 128;
    int lo = part * 2048, hi = lo + 2048;
    if (hi > total) hi = total;
    for (int idx = lo + threadIdx.x; idx < hi; idx += 256) {
        int k = idx >> 7, n = idx & 127;
        dst[n * K + k] = f2b(W[k * 128 + n]);
    }
}

// ---------- fused context + c1 precompute ----------
__global__ void k_ctx_c1(const float* __restrict__ focal, const float* __restrict__ Wseq,
                         const float* __restrict__ bseq, const float* __restrict__ Wa1c,
                         const float* __restrict__ ba1, float* __restrict__ c1) {
    __shared__ float cs[HH];
    int t = threadIdx.x;
    float acc = bseq[t];
    for (int d = 0; d < DD; ++d) acc = fmaf(focal[d], Wseq[d * HH + t], acc);
    cs[t] = acc;
    __syncthreads();
    float a2 = ba1[t];
    for (int k = 0; k < HH; ++k) a2 = fmaf(cs[k], Wa1c[k * HH + t], a2);
    c1[t] = a2;
}

__global__ void k_tproj(const float* __restrict__ tt, const float* __restrict__ Wa1m,
                        float* __restrict__ tproj) {
    int ti = blockIdx.x, t = threadIdx.x;
    float acc = 0.f;
    for (int k = 0; k < HH; ++k)
        acc = fmaf(tt[ti * HH + k], Wa1m[k * HH + t], acc);
    tproj[(size_t)ti * HH + t] = acc;
}

// ---------- merged CSR build (both directions in one 2N array) ----------
// counts[0..NN)   : BU (dst = ei row0), counts[NN..2NN) : TD (dst = ei row1)
__global__ void k_hist2(const int* __restrict__ ei, int* __restrict__ counts) {
    int e = blockIdx.x * 256 + threadIdx.x;
    if (e >= EE) return;
    atomicAdd(&counts[ei[e]], 1);
    atomicAdd(&counts[NN + ei[EE + e]], 1);
}

__global__ __launch_bounds__(256) void k_scan_block(const int* __restrict__ in,
                                                    int* __restrict__ out,
                                                    int* __restrict__ bsum, int n) {
    __shared__ int sh[256];
    int b = blockIdx.x, t = threadIdx.x;
    int base = b * 1024 + t * 4;
    int v0 = (base + 0 < n) ? in[base + 0] : 0;
    int v1 = (base + 1 < n) ? in[base + 1] : 0;
    int v2 = (base + 2 < n) ? in[base + 2] : 0;
    int v3 = (base + 3 < n) ? in[base + 3] : 0;
    int tsum = v0 + v1 + v2 + v3;
    sh[t] = tsum;
    __syncthreads();
    for (int d = 1; d < 256; d <<= 1) {
        int x = (t >= d) ? sh[t - d] : 0;
        __syncthreads();
        sh[t] += x;
        __syncthreads();
    }
    int excl = sh[t] - tsum;
    if (t == 255) bsum[b] = sh[255];
    if (base + 0 < n) out[base + 0] = excl;
    if (base + 1 < n) out[base + 1] = excl + v0;
    if (base + 2 < n) out[base + 2] = excl + v0 + v1;
    if (base + 3 < n) out[base + 3] = excl + v0 + v1 + v2;
}

__global__ __launch_bounds__(256) void k_scan_top(int* __restrict__ data, int n) {
    __shared__ int sh[256];
    int t = threadIdx.x;
    int base = t * 4;
    int v0 = (base + 0 < n) ? data[base + 0] : 0;
    int v1 = (base + 1 < n) ? data[base + 1] : 0;
    int v2 = (base + 2 < n) ? data[base + 2] : 0;
    int v3 = (base + 3 < n) ? data[base + 3] : 0;
    int tsum = v0 + v1 + v2 + v3;
    sh[t] = tsum;
    __syncthreads();
    for (int d = 1; d < 256; d <<= 1) {
        int x = (t >= d) ? sh[t - d] : 0;
        __syncthreads();
        sh[t] += x;
        __syncthreads();
    }
    int excl = sh[t] - tsum;
    if (base + 0 < n) data[base + 0] = excl;
    if (base + 1 < n) data[base + 1] = excl + v0;
    if (base + 2 < n) data[base + 2] = excl + v0 + v1;
    if (base + 3 < n) data[base + 3] = excl + v0 + v1 + v2;
}

__global__ void k_scan_add(int* __restrict__ out, const int* __restrict__ bsum, int n) {
    int i = blockIdx.x * 256 + threadIdx.x;
    if (i < n) out[i] += bsum[i >> 10];
}

__global__ void k_settail(int* offs) {
    if (threadIdx.x == 0) offs[2 * NN] = 2 * EE;
}

__global__ void k_scatter2(const int* __restrict__ ei, int* __restrict__ cursor,
                           int* __restrict__ elist) {
    int e = blockIdx.x * 256 + threadIdx.x;
    if (e >= EE) return;
    int r0 = ei[e], r1 = ei[EE + e];
    int pB = atomicAdd(&cursor[r0], 1);      elist[pB] = r1;  // BU: dst=r0 src=r1
    int pT = atomicAdd(&cursor[NN + r1], 1); elist[pT] = r0;  // TD: dst=r1 src=r0
}

// ---------- tile-local degree sort: perm 256-node windows by degree ----------
__global__ __launch_bounds__(256) void k_tilesort(const int* __restrict__ counts,
                                                  int* __restrict__ perm) {
    __shared__ int cur[16];
    int half = blockIdx.y;
    int base = blockIdx.x * 256;
    int t = threadIdx.x;
    int node = base + t;
    bool valid = node < NN;
    int deg = 0;
    if (valid) { deg = counts[half * NN + node]; if (deg > 15) deg = 15; }
    if (t < 16) cur[t] = 0;
    __syncthreads();
    if (valid) atomicAdd(&cur[deg], 1);
    __syncthreads();
    if (t == 0) {
        int run = 0;
#pragma unroll
        for (int b = 0; b < 16; ++b) { int c = cur[b]; cur[b] = run; run += c; }
    }
    __syncthreads();
    if (valid) {
        int pos = atomicAdd(&cur[deg], 1);
        perm[half * NN + base + pos] = node;
    }
}

// ============ MFMA GEMM (f32 input embed) ============
template <int K, typename InT>
__global__ __launch_bounds__(256) void k_mfma_proj(const InT* __restrict__ in,
                                                   const u16* __restrict__ WT,
                                                   const float* __restrict__ bias,
                                                   u16* __restrict__ out, int nrows) {
    __shared__ u16 lds[17408];
    u16* a_lds = lds;
    u16* b_lds = lds + 8192;
    u16* clds = lds;
    const int t = threadIdx.x;
    const int tile_m = blockIdx.x * 128;
    const int wave = t >> 6, l = t & 15, quad = (t >> 4) & 3;
    const int wr = wave >> 1, wc = wave & 1;
    f32x4 acc[4][4] = {};

    for (int chunk = 0; chunk < K / 64; ++chunk) {
        const int c0 = chunk * 64;
        __syncthreads();
        for (int ci = t; ci < 1024; ci += 256) {
            int row = ci >> 3, kc = ci & 7;
            int grow = tile_m + row;
            uint4 v = make_uint4(0, 0, 0, 0);
            if (grow < nrows) v = load8(&in[(size_t)grow * K + c0 + kc * 8]);
            *(uint4*)&a_lds[swo(row, kc)] = v;
        }
        for (int ci = t; ci < 1024; ci += 256) {
            int n = ci >> 3, kc = ci & 7;
            *(uint4*)&b_lds[swo(n, kc)] = *(const uint4*)&WT[(size_t)n * K + c0 + kc * 8];
        }
        __syncthreads();
#pragma unroll
        for (int ks = 0; ks < 2; ++ks) {
            short8 af[4], bf[4];
#pragma unroll
            for (int i = 0; i < 4; ++i)
                af[i] = *(const short8*)&a_lds[swo(wr * 64 + i * 16 + l, ks * 4 + quad)];
#pragma unroll
            for (int j = 0; j < 4; ++j)
                bf[j] = *(const short8*)&b_lds[swo(wc * 64 + j * 16 + l, ks * 4 + quad)];
#pragma unroll
            for (int i = 0; i < 4; ++i)
#pragma unroll
                for (int j = 0; j < 4; ++j)
                    acc[i][j] = __builtin_amdgcn_mfma_f32_16x16x32_bf16(af[i], bf[j], acc[i][j], 0, 0, 0);
        }
    }
    __syncthreads();
#pragma unroll
    for (int j = 0; j < 4; ++j) {
        int col = wc * 64 + j * 16 + l;
        float b = bias[col];
#pragma unroll
        for (int i = 0; i < 4; ++i) {
            int rloc = wr * 64 + i * 16 + quad * 4;
#pragma unroll
            for (int r = 0; r < 4; ++r)
                clds[(rloc + r) * 136 + col] = f2b(acc[i][j][r] + b);
        }
    }
    __syncthreads();
#pragma unroll
    for (int it = 0; it < 8; ++it) {
        int idx = it * 256 + t;
        int row = idx >> 4, c16 = idx & 15;
        int grow = tile_m + row;
        if (grow < nrows)
            *(uint4*)&out[(size_t)grow * HH + c16 * 8] = *(const uint4*)&clds[row * 136 + c16 * 8];
    }
}

// ============ fused dual GEMM, 512 threads / 8 waves ============
__global__ __launch_bounds__(512) void k_mfma_proj2(const u16* __restrict__ in,
                                                    const u16* __restrict__ WT1,
                                                    const u16* __restrict__ WT2,
                                                    const float* __restrict__ b1,
                                                    const float* __restrict__ b2,
                                                    u16* __restrict__ out1,
                                                    u16* __restrict__ out2, int nrows) {
    __shared__ u16 lds[24576];
    u16* a_lds = lds;
    u16* b1_lds = lds + 8192;
    u16* b2_lds = lds + 16384;
    u16* clds = lds;
    const int t = threadIdx.x;
    const int tile_m = blockIdx.x * 128;
    const int wave = t >> 6, l = t & 15, quad = (t >> 4) & 3;
    const int wr = wave >> 1, wc = wave & 1;
    f32x4 acc1[2][4] = {}, acc2[2][4] = {};

    for (int chunk = 0; chunk < 2; ++chunk) {
        const int c0 = chunk * 64;
        __syncthreads();
#pragma unroll
        for (int it = 0; it < 2; ++it) {
            int ci = it * 512 + t;
            int row = ci >> 3;
            int colblk = ((ci & 7) ^ (row & 7)) * 8;
            u16* wbase = lds + (ci & ~63) * 8;
            int grow = tile_m + row; if (grow >= nrows) grow = nrows - 1;
            gl_lds16(&in[(size_t)grow * HH + c0 + colblk], wbase);
            gl_lds16(&WT1[(size_t)row * HH + c0 + colblk], wbase + 8192);
            gl_lds16(&WT2[(size_t)row * HH + c0 + colblk], wbase + 16384);
        }
        __syncthreads();
#pragma unroll
        for (int ks = 0; ks < 2; ++ks) {
            short8 af[2], bf1[4], bf2[4];
#pragma unroll
            for (int i = 0; i < 2; ++i)
                af[i] = *(const short8*)&a_lds[swo(wr * 32 + i * 16 + l, ks * 4 + quad)];
#pragma unroll
            for (int j = 0; j < 4; ++j) {
                bf1[j] = *(const short8*)&b1_lds[swo(wc * 64 + j * 16 + l, ks * 4 + quad)];
                bf2[j] = *(const short8*)&b2_lds[swo(wc * 64 + j * 16 + l, ks * 4 + quad)];
            }
#pragma unroll
            for (int i = 0; i < 2; ++i)
#pragma unroll
                for (int j = 0; j < 4; ++j) {
                    acc1[i][j] = __builtin_amdgcn_mfma_f32_16x16x32_bf16(af[i], bf1[j], acc1[i][j], 0, 0, 0);
                    acc2[i][j] = __builtin_amdgcn_mfma_f32_16x16x32_bf16(af[i], bf2[j], acc2[i][j], 0, 0, 0);
                }
        }
    }
    // epilogue out1
    __syncthreads();
#pragma unroll
    for (int j = 0; j < 4; ++j) {
        int col = wc * 64 + j * 16 + l;
        float b = b1[col];
#pragma unroll
        for (int i = 0; i < 2; ++i) {
            int rloc = wr * 32 + i * 16 + quad * 4;
#pragma unroll
            for (int r = 0; r < 4; ++r)
                clds[(rloc + r) * 136 + col] = f2b(acc1[i][j][r] + b);
        }
    }
    __syncthreads();
#pragma unroll
    for (int it = 0; it < 4; ++it) {
        int idx = it * 512 + t;
        int row = idx >> 4, c16 = idx & 15;
        int grow = tile_m + row;
        if (grow < nrows)
            *(uint4*)&out1[(size_t)grow * HH + c16 * 8] = *(const uint4*)&clds[row * 136 + c16 * 8];
    }
    // epilogue out2
    __syncthreads();
#pragma unroll
    for (int j = 0; j < 4; ++j) {
        int col = wc * 64 + j * 16 + l;
        float b = b2[col];
#pragma unroll
        for (int i = 0; i < 2; ++i) {
            int rloc = wr * 32 + i * 16 + quad * 4;
#pragma unroll
            for (int r = 0; r < 4; ++r)
                clds[(rloc + r) * 136 + col] = f2b(acc2[i][j][r] + b);
        }
    }
    __syncthreads();
#pragma unroll
    for (int it = 0; it < 4; ++it) {
        int idx = it * 512 + t;
        int row = idx >> 4, c16 = idx & 15;
        int grow = tile_m + row;
        if (grow < nrows)
            *(uint4*)&out2[(size_t)grow * HH + c16 * 8] = *(const uint4*)&clds[row * 136 + c16 * 8];
    }
}

// ============ fused branch + z + logit ============
__global__ __launch_bounds__(256) void k_branch_logit(const u16* __restrict__ h,
                                                      const int* __restrict__ idx1,
                                                      const int* __restrict__ idx2,
                                                      const u16* __restrict__ WT1,
                                                      const u16* __restrict__ WT2,
                                                      const float* __restrict__ bias,
                                                      const int* __restrict__ time_idx,
                                                      const float* __restrict__ tproj,
                                                      const float* __restrict__ c1,
                                                      const u16* __restrict__ WTa1,
                                                      const float* __restrict__ Wa2,
                                                      const float* __restrict__ ba2,
                                                      float* __restrict__ out) {
    __shared__ u16 lds[24576];
    __shared__ float red[2][128];
    u16* a_lds = lds;
    u16* b_lds = lds + 8192;
    u16* abuf = lds;
    u16* z2 = lds + 16384;
    const int t = threadIdx.x;
    const int tile_m = blockIdx.x * 128;
    const int wave = t >> 6, l = t & 15, quad = (t >> 4) & 3;
    const int wr = wave >> 1, wc = wave & 1;
    f32x4 acc[4][4] = {};

    for (int pass = 0; pass < 2; ++pass) {
        const int* idx = pass ? idx2 : idx1;
        const u16* WT = pass ? WT2 : WT1;
        for (int chunk = 0; chunk < 2; ++chunk) {
            const int c0 = chunk * 64;
            __syncthreads();
            int gneg[4];
#pragma unroll
            for (int it = 0; it < 4; ++it) {
                int ci = it * 256 + t;
                int row = ci >> 3;
                int colblk = ((ci & 7) ^ (row & 7)) * 8;
                u16* wbase = lds + (ci & ~63) * 8;
                int item = tile_m + row; if (item >= AA) item = AA - 1;
                int g = idx[item];
                gneg[it] = (g < 0);
                if (g < 0) g = 0;
                gl_lds16(&h[(size_t)g * HH + c0 + colblk], wbase);
                gl_lds16(&WT[(size_t)row * HH + c0 + colblk], wbase + 8192);
            }
            __syncthreads();
#pragma unroll
            for (int it = 0; it < 4; ++it) {
                if (gneg[it]) {
                    int ci = it * 256 + t;
                    *(uint4*)&a_lds[ci * 8] = make_uint4(0, 0, 0, 0);
                }
            }
            __syncthreads();
#pragma unroll
            for (int ks = 0; ks < 2; ++ks) {
                short8 af[4], bf[4];
#pragma unroll
                for (int i = 0; i < 4; ++i)
                    af[i] = *(const short8*)&a_lds[swo(wr * 64 + i * 16 + l, ks * 4 + quad)];
#pragma unroll
                for (int j = 0; j < 4; ++j)
                    bf[j] = *(const short8*)&b_lds[swo(wc * 64 + j * 16 + l, ks * 4 + quad)];
#pragma unroll
                for (int i = 0; i < 4; ++i)
#pragma unroll
                    for (int j = 0; j < 4; ++j)
                        acc[i][j] = __builtin_amdgcn_mfma_f32_16x16x32_bf16(af[i], bf[j], acc[i][j], 0, 0, 0);
            }
        }
    }
    __syncthreads();
#pragma unroll
    for (int j = 0; j < 4; ++j) {
        int col = wc * 64 + j * 16 + l;
        float b = bias[col];
        int kb = col >> 3, ko = col & 7;
#pragma unroll
        for (int i = 0; i < 4; ++i) {
            int rloc = wr * 64 + i * 16 + quad * 4;
#pragma unroll
            for (int r = 0; r < 4; ++r)
                abuf[swo2(rloc + r, kb) + ko] = f2b(acc[i][j][r] + b);
        }
    }
    f32x4 accz[4][4] = {};
    for (int chunk = 0; chunk < 2; ++chunk) {
        const int c0 = chunk * 64;
        __syncthreads();
#pragma unroll
        for (int it = 0; it < 4; ++it) {
            int ci = it * 256 + t;
            int row = ci >> 3;
            int colblk = ((ci & 7) ^ (row & 7)) * 8;
            u16* wbase = z2 + (ci & ~63) * 8;
            gl_lds16(&WTa1[(size_t)row * HH + c0 + colblk], wbase);
        }
        __syncthreads();
#pragma unroll
        for (int ks = 0; ks < 2; ++ks) {
            short8 af[4], bf[4];
            int kb = chunk * 8 + ks * 4 + quad;
#pragma unroll
            for (int i = 0; i < 4; ++i)
                af[i] = *(const short8*)&abuf[swo2(wr * 64 + i * 16 + l, kb)];
#pragma unroll
            for (int j = 0; j < 4; ++j)
                bf[j] = *(const short8*)&z2[swo(wc * 64 + j * 16 + l, ks * 4 + quad)];
#pragma unroll
            for (int i = 0; i < 4; ++i)
#pragma unroll
                for (int j = 0; j < 4; ++j)
                    accz[i][j] = __builtin_amdgcn_mfma_f32_16x16x32_bf16(af[i], bf[j], accz[i][j], 0, 0, 0);
        }
    }
    float c1v[4], wa2v[4];
#pragma unroll
    for (int j = 0; j < 4; ++j) {
        int col = wc * 64 + j * 16 + l;
        c1v[j] = c1[col];
        wa2v[j] = Wa2[col];
    }
#pragma unroll
    for (int i = 0; i < 4; ++i) {
        int rbase = tile_m + wr * 64 + i * 16 + quad * 4;
#pragma unroll
        for (int r = 0; r < 4; ++r) {
            int item = rbase + r;
            int ti = (item < AA) ? time_idx[item] : 0;
            const float* tp = tproj + (size_t)ti * HH;
            float partial = 0.f;
#pragma unroll
            for (int j = 0; j < 4; ++j) {
                int col = wc * 64 + j * 16 + l;
                float z = fmaxf(accz[i][j][r] + tp[col] + c1v[j], 0.f);
                partial = fmaf(z, wa2v[j], partial);
            }
            partial += __shfl_xor(partial, 1);
            partial += __shfl_xor(partial, 2);
            partial += __shfl_xor(partial, 4);
            partial += __shfl_xor(partial, 8);
            if (l == 0) red[wc][wr * 64 + i * 16 + quad * 4 + r] = partial;
        }
    }
    __syncthreads();
    if (t < 128) {
        int item = tile_m + t;
        if (item < AA) out[item] = red[0][t] + red[1][t] + ba2[0];
    }
}

// ============ fused GAT: single-pass online softmax + aggregation + h update (perm'd) ============
__global__ __launch_bounds__(256) void k_gat_fused(u16* __restrict__ h,
                                                   const u16* __restrict__ xl,
                                                   const u16* __restrict__ xr,
                                                   const int* __restrict__ offs,
                                                   const int* __restrict__ elist,
                                                   const int* __restrict__ perm,
                                                   const float* __restrict__ att,
                                                   const float* __restrict__ bias) {
    int g = perm[blockIdx.x * 16 + (threadIdx.x >> 4)];   // degree-sorted node
    int l = threadIdx.x & 15;
    float attv[8], biasv[8];
    *(float4*)&attv[0] = *(const float4*)&att[l * 8];
    *(float4*)&attv[4] = *(const float4*)&att[l * 8 + 4];
    *(float4*)&biasv[0] = *(const float4*)&bias[l * 8];
    *(float4*)&biasv[4] = *(const float4*)&bias[l * 8 + 4];
    float xrf[8];
    unpack8(*(const uint4*)&xr[(size_t)g * HH + l * 8], xrf);
    int e0 = offs[g], e1 = offs[g + 1];

    float m = -__builtin_inff(), s = 0.f;
    float acc[8] = {};
    for (int e = e0; e < e1; ++e) {
        int sidx = elist[e];
        float xf[8];
        unpack8(*(const uint4*)&xl[(size_t)sidx * HH + l * 8], xf);
        float p = 0.f;
#pragma unroll
        for (int j = 0; j < 8; ++j) {
            float v = xf[j] + xrf[j];
            v = v >= 0.f ? v : 0.2f * v;
            p = fmaf(v, attv[j], p);
        }
        p += __shfl_xor(p, 1); p += __shfl_xor(p, 2);
        p += __shfl_xor(p, 4); p += __shfl_xor(p, 8);
        float mn = fmaxf(m, p);
        float so = __expf(m - mn);
        float w = __expf(p - mn);
        s = s * so + w;
#pragma unroll
        for (int j = 0; j < 8; ++j) acc[j] = fmaf(acc[j], so, w * xf[j]);
        m = mn;
    }
    float inv = 1.f / (s + 1e-16f);

    float hf[8];
    unpack8(*(const uint4*)&h[(size_t)g * HH + l * 8], hf);
    union { ushort sh[8]; uint4 v; } o;
#pragma unroll
    for (int j = 0; j < 8; ++j) {
        hf[j] += fmaxf(fmaf(acc[j], inv, biasv[j]), 0.f);
        o.sh[j] = f2b(hf[j]);
    }
    *(uint4*)&h[(size_t)g * HH + l * 8] = o.v;
}

// ---------- host side ----------
typedef const float* fp;

extern "C" void kernel_launch(void* const* d_in, const int* in_sizes, int n_in,
                              void* d_out, int out_size, void* d_ws, size_t ws_size,
                              hipStream_t stream) {
    fp x                 = (fp)d_in[0];
    const int* ei        = (const int*)d_in[1];
    fp focal             = (fp)d_in[2];
    const int* child_idx = (const int*)d_in[3];
    const int* parent_idx= (const int*)d_in[4];
    const int* time_idx  = (const int*)d_in[5];
    fp W_embed = (fp)d_in[6],  b_embed = (fp)d_in[7];
    fp bu_Wl   = (fp)d_in[8],  bu_bl   = (fp)d_in[9];
    fp bu_Wr   = (fp)d_in[10], bu_br   = (fp)d_in[11];
    fp bu_att  = (fp)d_in[12], bu_bias = (fp)d_in[13];
    fp td_Wl   = (fp)d_in[14], td_bl   = (fp)d_in[15];
    fp td_Wr   = (fp)d_in[16], td_br   = (fp)d_in[17];
    fp td_att  = (fp)d_in[18], td_bias = (fp)d_in[19];
    fp time_table = (fp)d_in[20];
    fp W_comb  = (fp)d_in[21], b_comb  = (fp)d_in[22];
    fp W_a1    = (fp)d_in[23], b_a1    = (fp)d_in[24];
    fp W_a2    = (fp)d_in[25], b_a2    = (fp)d_in[26];
    fp W_seq   = (fp)d_in[27], b_seq   = (fp)d_in[28];

    const size_t NH = (size_t)NN * HH;
    u16* wt = (u16*)d_ws;                 // 8 x 16384 u16 (256 KB)
    u16* h  = wt + 8 * 16384;             // N*H bf16
    u16* xl = h + NH;
    u16* xr = xl + NH;
    float* c1v   = (float*)(xr + NH);     // H
    float* tproj = c1v + HH;              // T*H
    int* offs    = (int*)(tproj + (size_t)TT * HH);  // 2N+1
    int* elist   = offs + 2 * NN + 1;                // 2E
    int* counts  = elist + 2 * EE;                   // 2N (degrees)
    int* cursor  = counts + 2 * NN;                  // 2N
    int* perm    = cursor + 2 * NN;                  // 2N
    int* bsum    = perm + 2 * NN;                    // SCAN_NB2

    // merged CSR build: BU (dst=row0) in [0,NN), TD (dst=row1) in [NN,2NN)
    hipMemsetAsync(counts, 0, (size_t)2 * NN * 4, stream);
    k_hist2<<<(EE + 255) / 256, 256, 0, stream>>>(ei, counts);
    k_scan_block<<<SCAN_NB2, 256, 0, stream>>>(counts, offs, bsum, 2 * NN);
    k_scan_top<<<1, 256, 0, stream>>>(bsum, SCAN_NB2);
    k_scan_add<<<(2 * NN + 255) / 256, 256, 0, stream>>>(offs, bsum, 2 * NN);
    k_settail<<<1, 64, 0, stream>>>(offs);
    k_tilesort<<<dim3((NN + 255) / 256, 2), 256, 0, stream>>>(counts, perm);
    hipMemcpyAsync(cursor, offs, (size_t)2 * NN * 4, hipMemcpyDeviceToDevice, stream);
    k_scatter2<<<(EE + 255) / 256, 256, 0, stream>>>(ei, cursor, elist);

    // pre-transpose all GEMM weights to bf16 [n][k]
    k_wtrans<<<64, 256, 0, stream>>>(bu_Wl, bu_Wr, td_Wl, td_Wr,
                                     W_comb, W_comb + (size_t)HH * HH, W_a1, W_embed, wt);
    const u16* wt_buWl = wt + 0 * 16384;
    const u16* wt_buWr = wt + 1 * 16384;
    const u16* wt_tdWl = wt + 2 * 16384;
    const u16* wt_tdWr = wt + 3 * 16384;
    const u16* wt_combC = wt + 4 * 16384;
    const u16* wt_combP = wt + 5 * 16384;
    const u16* wt_a1   = wt + 6 * 16384;
    const u16* wt_embed = wt + 7 * 16384;

    // small precomputes
    k_ctx_c1<<<1, 128, 0, stream>>>(focal, W_seq, b_seq, W_a1 + (size_t)256 * HH, b_a1, c1v);
    k_tproj<<<TT, 128, 0, stream>>>(time_table, W_a1 + (size_t)128 * HH, tproj);

    const int NB = (NN + 127) / 128;
    // embed
    k_mfma_proj<64, float><<<NB, 256, 0, stream>>>(x, wt_embed, b_embed, h, NN);

    // bottom-up GAT
    k_mfma_proj2<<<NB, 512, 0, stream>>>(h, wt_buWl, wt_buWr, bu_bl, bu_br, xl, xr, NN);
    k_gat_fused<<<NN / 16, 256, 0, stream>>>(h, xl, xr, offs, elist, perm, bu_att, bu_bias);

    // top-down GAT
    k_mfma_proj2<<<NB, 512, 0, stream>>>(h, wt_tdWl, wt_tdWr, td_bl, td_br, xl, xr, NN);
    k_gat_fused<<<NN / 16, 256, 0, stream>>>(h, xl, xr, offs + NN, elist, perm + NN, td_att, td_bias);

    // branch + z + logit fused
    k_branch_logit<<<(AA + 127) / 128, 256, 0, stream>>>(
        h, child_idx, parent_idx, wt_combC, wt_combP, b_comb,
        time_idx, tproj, c1v, wt_a1, W_a2, b_a2, (float*)d_out);
}